// Round 6
// baseline (261.193 us; speedup 1.0000x reference)
//
#include <hip/hip_runtime.h>
#include <stdint.h>

// ---------------- constants ----------------
#define T_SEQ 2048
#define DM    2048
#define NH    16
#define HD    128
#define SB    204          // int(0.1*2048)
#define EV    1229         // 2048 - 819
#define RB    819          // int(0.4*2048)
#define NRECF 818.0f       // 2048 - (EV+1)
#define LAST_START 1792    // (2047//256)*256
#define SCALE 0.08838834764831845f  // 1/sqrt(128)

typedef __attribute__((ext_vector_type(8))) short short8;
typedef __attribute__((ext_vector_type(4))) short short4v;
typedef __attribute__((ext_vector_type(4))) float f32x4;

__device__ __forceinline__ unsigned short f2bf(float f) {
  uint32_t u = __float_as_uint(f);
  u += 0x7fffu + ((u >> 16) & 1u);   // RNE
  return (unsigned short)(u >> 16);
}
__device__ __forceinline__ float bf2f(unsigned short s) {
  return __uint_as_float(((uint32_t)s) << 16);
}
__device__ __forceinline__ void gload16(const void* g, void* l) {
  __builtin_amdgcn_global_load_lds((const __attribute__((address_space(1))) void*)g,
                                   (__attribute__((address_space(3))) void*)l,
                                   16, 0, 0);
}
__device__ __forceinline__ float n2n(float v) {
  if (isnan(v)) return 0.0f;
  if (isinf(v)) return v > 0.0f ? 10000.0f : -10000.0f;
  return v;
}

// ---------------- 1. fp32 -> bf16 conversions + RoPE table (fused) ----------------
__global__ __launch_bounds__(256) void cvt_kernel(
    const float* __restrict__ hs, const float* __restrict__ wq,
    const float* __restrict__ wk, const float* __restrict__ wv,
    const float* __restrict__ wo, unsigned short* __restrict__ hsb,
    unsigned short* __restrict__ wqb, unsigned short* __restrict__ wkb,
    unsigned short* __restrict__ wvb, unsigned short* __restrict__ wob,
    float* __restrict__ cst, float* __restrict__ snt) {
  if (blockIdx.x >= 20480) {   // RoPE cos/sin table tail blocks
    int idx = (blockIdx.x - 20480) * 256 + threadIdx.x;   // 2048*64
    int t = idx >> 6, i = idx & 63;
    float inv = (float)exp(-(double)i * log(10000.0) / 64.0);
    float ang = (float)t * inv;
    cst[idx] = (float)cos((double)ang);
    snt[idx] = (float)sin((double)ang);
    return;
  }
  int gid = blockIdx.x * 256 + threadIdx.x;
  int region = gid >> 20;
  int off4 = (gid & 1048575) * 4;
  const float* src; unsigned short* dst;
  switch (region) {
    case 0: src = hs; dst = hsb; break;
    case 1: src = wq; dst = wqb; break;
    case 2: src = wk; dst = wkb; break;
    case 3: src = wv; dst = wvb; break;
    default: src = wo; dst = wob; break;
  }
  float4 v = *(const float4*)(src + off4);
  if (region == 0) { v.x = n2n(v.x); v.y = n2n(v.y); v.z = n2n(v.z); v.w = n2n(v.w); }
  ushort4 o;
  o.x = f2bf(v.x); o.y = f2bf(v.y); o.z = f2bf(v.z); o.w = f2bf(v.w);
  *(ushort4*)(dst + off4) = o;
}

// ---------------- shared BK=64 GEMM mainloop (single-buffer, proven round-0) ----------------
// C[128x128] tile, A[M,K] @ B[N,K]^T bf16. LDS rows = 128 B (8 x 16B chunks),
// XOR-swizzled: phys chunk = logical ^ (row & 7), folded into global src addr.
// tid is GROUP-LOCAL (0..255): callable by multi-group blocks whose groups share
// the workgroup barrier (identical barrier cadence in every group).
__device__ __forceinline__ void gemm_mainloop64(
    const unsigned short* __restrict__ A, const unsigned short* __restrict__ B,
    unsigned short* As, unsigned short* Bs, int m0, int n0, int k0, int ksteps,
    int tid, f32x4 (&acc)[4][4]) {
  int w = tid >> 6, lane = tid & 63;
  int wm = w >> 1, wn = w & 1;
  int q4 = lane >> 4, r = lane & 15;
  f32x4 zero = {0.f, 0.f, 0.f, 0.f};
  #pragma unroll
  for (int mi = 0; mi < 4; mi++)
    #pragma unroll
    for (int ni = 0; ni < 4; ni++) acc[mi][ni] = zero;
  int srow = w * 32 + (lane >> 3);
  int swz = ((lane & 7) ^ (lane >> 3)) * 16;
  const char* Ag = (const char*)(A + (size_t)(m0 + srow) * DM) + swz + k0 * 2;
  const char* Bg = (const char*)(B + (size_t)(n0 + srow) * DM) + swz + k0 * 2;
  unsigned short* Asl = As + w * 2048;
  unsigned short* Bsl = Bs + w * 2048;
  for (int s = 0; s < ksteps; s++) {
    __syncthreads();
    #pragma unroll
    for (int g = 0; g < 4; g++) {
      gload16(Ag + g * (8 * DM * 2), Asl + g * 512);
      gload16(Bg + g * (8 * DM * 2), Bsl + g * 512);
    }
    Ag += 128; Bg += 128;   // advance 64 cols
    __syncthreads();
    #pragma unroll
    for (int kh = 0; kh < 2; kh++) {
      int pcs = ((kh * 4 + q4) ^ (r & 7)) * 8;
      short8 a[4], b[4];
      #pragma unroll
      for (int mi = 0; mi < 4; mi++)
        a[mi] = *(const short8*)(As + (wm * 64 + mi * 16 + r) * 64 + pcs);
      #pragma unroll
      for (int ni = 0; ni < 4; ni++)
        b[ni] = *(const short8*)(Bs + ((ni & 1) * 64 + wn * 32 + (ni >> 1) * 16 + r) * 64 + pcs);
      #pragma unroll
      for (int mi = 0; mi < 4; mi++)
        #pragma unroll
        for (int ni = 0; ni < 4; ni++)
          acc[mi][ni] = __builtin_amdgcn_mfma_f32_16x16x32_bf16(a[mi], b[ni], acc[mi][ni], 0, 0, 0);
    }
  }
}

// ---------------- 3. fused QKV GEMM + RoPE / V-transpose, masked-row cut ----------------
// grid y in [0,34): y<16 -> Q tile y; y<25 -> K tile map[y-16]; else V tile map[y-25]
// where map = {0,1,9..15} (only M-tiles containing kept key rows [0,224)U[1216,2048)).
__global__ __launch_bounds__(256, 3) void gemm_qkv_kernel(
    const unsigned short* __restrict__ hsb, const unsigned short* __restrict__ wqb,
    const unsigned short* __restrict__ wkb, const unsigned short* __restrict__ wvb,
    const float* __restrict__ cst, const float* __restrict__ snt,
    unsigned short* __restrict__ qbf, unsigned short* __restrict__ kbf,
    unsigned short* __restrict__ vbT) {
  __shared__ __align__(16) unsigned short LDSBUF[17408];  // As(16KB)+Bs(16KB); vtile reuses
  unsigned short* As = LDSBUF;
  unsigned short* Bs = LDSBUF + 8192;
  int y = blockIdx.y;
  int z, mi;
  if (y < 16)      { z = 0; mi = y; }
  else if (y < 25) { z = 1; mi = y - 16; }
  else             { z = 2; mi = y - 25; }
  if (z) mi = (mi < 2) ? mi : mi + 7;
  const unsigned short* B = (z == 0) ? wqb : (z == 1) ? wkb : wvb;
  int m0 = mi * 128, n0 = blockIdx.x * 128;
  f32x4 acc[4][4];
  gemm_mainloop64(hsb, B, As, Bs, m0, n0, 0, DM / 64, threadIdx.x, acc);
  int tid = threadIdx.x, w = tid >> 6, lane = tid & 63;
  int wm = w >> 1, wn = w & 1, q4 = lane >> 4, r = lane & 15;
  int h = n0 >> 7;
  if (z < 2) {
    unsigned short* dst = (z == 0) ? qbf : kbf;
    #pragma unroll
    for (int mj = 0; mj < 4; mj++)
      #pragma unroll
      for (int p = 0; p < 2; p++) {
        int d = wn * 32 + p * 16 + r;
        #pragma unroll
        for (int g = 0; g < 4; g++) {
          int t = m0 + wm * 64 + mj * 16 + q4 * 4 + g;
          float c = cst[t * 64 + d], s = snt[t * 64 + d];
          float x0 = acc[mj][2 * p][g], x1 = acc[mj][2 * p + 1][g];
          dst[((size_t)h * T_SEQ + t) * HD + d]      = f2bf(x0 * c - x1 * s);
          dst[((size_t)h * T_SEQ + t) * HD + d + 64] = f2bf(x1 * c + x0 * s);
        }
      }
  } else {
    // transpose C tile (t,d) -> vbT[h][d][t] via LDS (Tpad=136)
    __syncthreads();
    #pragma unroll
    for (int mj = 0; mj < 4; mj++)
      #pragma unroll
      for (int ni = 0; ni < 4; ni++) {
        int c = (ni & 1) * 64 + wn * 32 + (ni >> 1) * 16 + r;
        int tl = wm * 64 + mj * 16 + q4 * 4;
        short4v pv;
        pv[0] = (short)f2bf(acc[mj][ni][0]);
        pv[1] = (short)f2bf(acc[mj][ni][1]);
        pv[2] = (short)f2bf(acc[mj][ni][2]);
        pv[3] = (short)f2bf(acc[mj][ni][3]);
        *(short4v*)(LDSBUF + c * 136 + tl) = pv;
      }
    __syncthreads();
    int d = tid >> 1, th = tid & 1;
    unsigned short* gdst = vbT + ((size_t)h * HD + d) * T_SEQ + m0 + th * 64;
    const unsigned short* lsrc = LDSBUF + d * 136 + th * 64;
    #pragma unroll
    for (int j = 0; j < 8; j++)
      *(short8*)(gdst + j * 8) = *(const short8*)(lsrc + j * 8);
  }
}

// ---------------- 4. flash attention, 64-key super-chunks, cross-iter dbuf ----------------
// Merged body (round-5): both 32-key sub-chunks in one pass with separate Ps
// buffers; setprio around MFMA clusters. This round: kernel split into TWO
// launches over h (diagnostic: halves become visible in rocprof top-5 if attn
// is the hidden-time owner).
__device__ __forceinline__ void attn_body2(
    int kb, const unsigned short* Kt0, const unsigned short* Kt1,
    const unsigned short* Vt0, const unsigned short* Vt1,
    const unsigned short* ind0, const unsigned short* ind1,
    unsigned short* Ps0, unsigned short* Ps1,
    const short8 (&aq)[4], f32x4 (&o)[8], f32x4& o9, float (&evf)[4],
    int q4, int r) {
  f32x4 zero = {0.f, 0.f, 0.f, 0.f};
  int rsw = (r >> 1) & 3;
  f32x4 sA0 = zero, sA1 = zero, sB0 = zero, sB1 = zero;
  __builtin_amdgcn_s_setprio(1);
  #pragma unroll
  for (int c = 0; c < 4; c++) {
    int pc = ((c * 4 + q4) ^ r) * 8;
    short8 kA0 = *(const short8*)(Kt0 + r * 128 + pc);
    short8 kA1 = *(const short8*)(Kt0 + (16 + r) * 128 + pc);
    short8 kB0 = *(const short8*)(Kt1 + r * 128 + pc);
    short8 kB1 = *(const short8*)(Kt1 + (16 + r) * 128 + pc);
    sA0 = __builtin_amdgcn_mfma_f32_16x16x32_bf16(aq[c], kA0, sA0, 0, 0, 0);
    sA1 = __builtin_amdgcn_mfma_f32_16x16x32_bf16(aq[c], kA1, sA1, 0, 0, 0);
    sB0 = __builtin_amdgcn_mfma_f32_16x16x32_bf16(aq[c], kB0, sB0, 0, 0, 0);
    sB1 = __builtin_amdgcn_mfma_f32_16x16x32_bf16(aq[c], kB1, sB1, 0, 0, 0);
  }
  __builtin_amdgcn_s_setprio(0);
  int kgA0 = kb + r, kgA1 = kb + 16 + r, kgB0 = kb + 32 + r, kgB1 = kb + 48 + r;
  bool keepA0 = (kgA0 < SB) || (kgA0 >= EV);
  bool keepA1 = (kgA1 < SB) || (kgA1 >= EV);
  bool keepB0 = (kgB0 < SB) || (kgB0 >= EV);
  bool keepB1 = (kgB1 < SB) || (kgB1 >= EV);
  #pragma unroll
  for (int g = 0; g < 4; g++) {
    float pA0 = keepA0 ? __expf(fmaf(sA0[g], SCALE, -8.0f)) : 0.0f;
    float pA1 = keepA1 ? __expf(fmaf(sA1[g], SCALE, -8.0f)) : 0.0f;
    float pB0 = keepB0 ? __expf(fmaf(sB0[g], SCALE, -8.0f)) : 0.0f;
    float pB1 = keepB1 ? __expf(fmaf(sB1[g], SCALE, -8.0f)) : 0.0f;
    if (kb == 1216 && kgA0 == EV) evf[g] = pA0;   // fp32 capture of p(k=1229)
    int row = q4 * 4 + g;
    int psw = (row >> 1) & 3;
    int c0 = (((r >> 3) ^ psw) * 8) + (r & 7);
    int c1 = ((((r >> 3) + 2) ^ psw) * 8) + (r & 7);
    Ps0[row * 32 + c0] = f2bf(pA0);
    Ps0[row * 32 + c1] = f2bf(pA1);
    Ps1[row * 32 + c0] = f2bf(pB0);
    Ps1[row * 32 + c1] = f2bf(pB1);
  }
  short8 pa0 = *(const short8*)(Ps0 + r * 32 + (q4 ^ rsw) * 8);
  short8 pa1 = *(const short8*)(Ps1 + r * 32 + (q4 ^ rsw) * 8);
  __builtin_amdgcn_s_setprio(1);
  #pragma unroll
  for (int ni = 0; ni < 8; ni++) {
    short8 bv0 = *(const short8*)(Vt0 + (ni * 16 + r) * 32 + (q4 ^ rsw) * 8);
    short8 bv1 = *(const short8*)(Vt1 + (ni * 16 + r) * 32 + (q4 ^ rsw) * 8);
    o[ni] = __builtin_amdgcn_mfma_f32_16x16x32_bf16(pa0, bv0, o[ni], 0, 0, 0);
    o[ni] = __builtin_amdgcn_mfma_f32_16x16x32_bf16(pa1, bv1, o[ni], 0, 0, 0);
  }
  short8 bi0 = *(const short8*)(ind0 + r * 32 + (q4 ^ rsw) * 8);
  short8 bi1 = *(const short8*)(ind1 + r * 32 + (q4 ^ rsw) * 8);
  o9 = __builtin_amdgcn_mfma_f32_16x16x32_bf16(pa0, bi0, o9, 0, 0, 0);
  o9 = __builtin_amdgcn_mfma_f32_16x16x32_bf16(pa1, bi1, o9, 0, 0, 0);
  __builtin_amdgcn_s_setprio(0);
}

__global__ __launch_bounds__(256, 2) void attn_kernel(
    const unsigned short* __restrict__ qbf, const unsigned short* __restrict__ kbf,
    const unsigned short* __restrict__ vbT, unsigned short* __restrict__ atb,
    float* __restrict__ attnf_s, float* __restrict__ Ssum, float* __restrict__ lst,
    int h0) {
  __shared__ __align__(16) unsigned short KtS[2][2][4096];  // [dbuf][sub][32x128u]
  __shared__ __align__(16) unsigned short VtS[2][2][4096];  // [dbuf][sub][128x32u]
  __shared__ __align__(16) unsigned short Ps[4][2][512];    // per-wave, per-sub-chunk
  __shared__ __align__(16) unsigned short Ind[3 * 512];
  int tid = threadIdx.x, w = tid >> 6, lane = tid & 63;
  int q4 = lane >> 4, r = lane & 15;
  int h = blockIdx.y + h0;
  int qb = blockIdx.x * 64 + w * 16;

  for (int idx = tid; idx < 3 * 512; idx += 256) {
    int v = idx >> 9, n = (idx >> 5) & 15, j = idx & 31;
    float val = 0.f;
    if (n == 0) val = 1.f;
    else if (n == 1) val = (v == 1) ? (j >= 14 ? 1.f : 0.f) : (v == 2 ? 1.f : 0.f);
    Ind[v * 512 + n * 32 + (((j >> 3) ^ ((n >> 1) & 3)) * 8) + (j & 7)] = f2bf(val);
  }

  short8 aq[4];
  {
    const unsigned short* qrow = qbf + ((size_t)h * T_SEQ + qb + r) * HD;
    #pragma unroll
    for (int c = 0; c < 4; c++) aq[c] = *(const short8*)(qrow + c * 32 + q4 * 8);
  }
  f32x4 zero = {0.f, 0.f, 0.f, 0.f};
  f32x4 o[8], o9;
  #pragma unroll
  for (int ni = 0; ni < 8; ni++) o[ni] = zero;
  o9 = zero;
  float evf[4] = {0.f, 0.f, 0.f, 0.f};

  const char* Kbase = (const char*)(kbf + (size_t)h * T_SEQ * HD);
  int krow0 = w * 8 + q4, krow1 = krow0 + 4;
  const char* Kg0 = Kbase + krow0 * 256 + ((r ^ (krow0 & 15)) * 16);
  const char* Kg1 = Kbase + krow1 * 256 + ((r ^ (krow1 & 15)) * 16);
  const char* Vbase = (const char*)(vbT + (size_t)h * HD * T_SEQ);
  int vsrc = ((lane & 3) ^ ((lane >> 3) & 3)) * 16;
  const char* Vg0 = Vbase + (size_t)(w * 32 + (lane >> 2)) * 4096 + vsrc;
  const char* Vg1 = Vg0 + 16 * 4096;

  auto issue_chunk = [&](int ci, int db) {
    int kb = (ci < 4) ? ci * 64 : 1216 + (ci - 4) * 64;
    gload16(Kg0 + kb * 256,         &KtS[db][0][w * 1024]);
    gload16(Kg1 + kb * 256,         &KtS[db][0][w * 1024 + 512]);
    gload16(Kg0 + (kb + 32) * 256,  &KtS[db][1][w * 1024]);
    gload16(Kg1 + (kb + 32) * 256,  &KtS[db][1][w * 1024 + 512]);
    gload16(Vg0 + kb * 2,           &VtS[db][0][w * 1024]);
    gload16(Vg1 + kb * 2,           &VtS[db][0][w * 1024 + 512]);
    gload16(Vg0 + (kb + 32) * 2,    &VtS[db][1][w * 1024]);
    gload16(Vg1 + (kb + 32) * 2,    &VtS[db][1][w * 1024 + 512]);
  };

  issue_chunk(0, 0);
  for (int ci = 0; ci < 17; ci++) {
    int db = ci & 1;
    int kb = (ci < 4) ? ci * 64 : 1216 + (ci - 4) * 64;
    const unsigned short* indA = Ind + ((ci < 4) ? 0 : (ci == 4) ? 512 : 1024);
    const unsigned short* indB = Ind + ((ci < 4) ? 0 : 1024);
    __syncthreads();
    if (ci < 16) issue_chunk(ci + 1, db ^ 1);
    attn_body2(kb, KtS[db][0], KtS[db][1], VtS[db][0], VtS[db][1],
               indA, indB, &Ps[w][0][0], &Ps[w][1][0], aq, o, o9, evf, q4, r);
  }

  float invl[4], srn[4], evn[4];
  #pragma unroll
  for (int g = 0; g < 4; g++) {
    float l  = __shfl(o9[g], lane & 48, 64);
    float sr = __shfl(o9[g], (lane & 48) | 1, 64);
    float ev = __shfl(evf[g], (lane & 48) | 13, 64);
    invl[g] = 1.0f / l;
    srn[g] = sr * invl[g];
    evn[g] = ev * invl[g];
  }
  if (blockIdx.x < (LAST_START / 64)) {
    #pragma unroll
    for (int ni = 0; ni < 8; ni++)
      #pragma unroll
      for (int g = 0; g < 4; g++)
        atb[(size_t)(qb + q4 * 4 + g) * DM + h * HD + ni * 16 + r] = f2bf(o[ni][g] * invl[g]);
  } else {
    #pragma unroll
    for (int ni = 0; ni < 8; ni++)
      #pragma unroll
      for (int g = 0; g < 4; g++)
        attnf_s[(size_t)(qb - LAST_START + q4 * 4 + g) * DM + h * HD + ni * 16 + r] = o[ni][g] * invl[g];
  }
  if (r == 0) {
    #pragma unroll
    for (int g = 0; g < 4; g++) {
      int t = qb + q4 * 4 + g;
      if (t >= LAST_START) Ssum[h * 256 + (t - LAST_START)] = srn[g];
      if (t == T_SEQ - 1) { lst[h * 2] = evn[g]; lst[h * 2 + 1] = srn[g]; }
    }
  }
}

// ---------------- 5. rank-1 eviction fixup (rows >= 1792), bern inlined ----------------
__device__ __forceinline__ void tf_round(uint32_t& x0, uint32_t& x1, int rot) {
  x0 += x1;
  x1 = (x1 << rot) | (x1 >> (32 - rot));
  x1 ^= x0;
}
__device__ __forceinline__ float bern_scale(int hh, const float* lst) {
  const uint32_t k0 = 0u, k1 = 42u, k2 = 0x1BD11BDAu ^ k0 ^ k1;
  uint32_t x0 = (uint32_t)(hh & 7), x1 = (uint32_t)((hh & 7) + 8);
  x0 += k0; x1 += k1;
  tf_round(x0, x1, 13); tf_round(x0, x1, 15); tf_round(x0, x1, 26); tf_round(x0, x1, 6);
  x0 += k1; x1 += k2 + 1u;
  tf_round(x0, x1, 17); tf_round(x0, x1, 29); tf_round(x0, x1, 16); tf_round(x0, x1, 24);
  x0 += k2; x1 += k0 + 2u;
  tf_round(x0, x1, 13); tf_round(x0, x1, 15); tf_round(x0, x1, 26); tf_round(x0, x1, 6);
  x0 += k0; x1 += k1 + 3u;
  tf_round(x0, x1, 17); tf_round(x0, x1, 29); tf_round(x0, x1, 16); tf_round(x0, x1, 24);
  x0 += k1; x1 += k2 + 4u;
  tf_round(x0, x1, 13); tf_round(x0, x1, 15); tf_round(x0, x1, 26); tf_round(x0, x1, 6);
  x0 += k2; x1 += k0 + 5u;
  uint32_t bits = (hh < 8) ? x0 : x1;
  float u = __uint_as_float((bits >> 9) | 0x3f800000u) - 1.0f;
  float evp = lst[hh * 2], srp = lst[hh * 2 + 1];
  float mean = srp * (1.0f / NRECF) + 1e-6f;
  float p = evp / mean;
  p = fminf(fmaxf(p, 0.0f), 1.0f);
  if (!(p == p)) p = 0.0f;
  return (u < p) ? (1.0f / (float)RB) : 0.0f;
}

__global__ __launch_bounds__(256) void fixup_kernel(
    const float* __restrict__ attnf_s, const float* __restrict__ Ssum,
    const float* __restrict__ lst, const unsigned short* __restrict__ vbT,
    unsigned short* __restrict__ atb) {
  int idx = blockIdx.x * 256 + threadIdx.x;   // 256*2048
  int t2 = idx >> 11, n = idx & 2047;
  int h = n >> 7, d = n & 127;
  float bsc = bern_scale(h, lst);
  float v = attnf_s[idx];
  v += Ssum[h * 256 + t2] * bsc * bf2f(vbT[((size_t)h * HD + d) * T_SEQ + EV]);
  atb[(size_t)(t2 + LAST_START) * DM + n] = f2bf(v);
}

// ---------------- 6. output projection GEMM, in-block split-K=2, fused add+n2n ----------------
// 512 threads = 2 groups x 4 waves; group g computes K [g*1024, g*1024+1024) with
// the proven mainloop (identical barrier cadence in both groups -> shared
// __syncthreads aligns). Group 1 parks acc in LDS (lane-contiguous idx*256+ltid,
// conflict-free), group 0 adds + nan_to_num + writes fp32 d_out directly.
// Eliminates part0/part1 (32 MB writes + 32 MB reads) and add_kernel.
__global__ __launch_bounds__(512, 2) void gemm_out_kernel(
    const unsigned short* __restrict__ atb, const unsigned short* __restrict__ wob,
    float* __restrict__ out) {
  __shared__ __align__(16) unsigned short LDSBUF[32768];  // 64 KB: 2x(As+Bs); reused as f32 C-exchange
  int tid = threadIdx.x;
  int grp = tid >> 8;          // 0: K 0..1023, 1: K 1024..2047
  int ltid = tid & 255;
  unsigned short* As = LDSBUF + grp * 16384;
  unsigned short* Bs = As + 8192;
  int m0 = blockIdx.y * 128, n0 = blockIdx.x * 128;
  f32x4 acc[4][4];
  gemm_mainloop64(atb, wob, As, Bs, m0, n0, grp * 1024, 16, ltid, acc);
  float* Cx = (float*)LDSBUF;  // 64 KB = [64 idx][256 ltid] f32
  __syncthreads();             // all waves done with staging LDS
  if (grp) {
    #pragma unroll
    for (int mi = 0; mi < 4; mi++)
      #pragma unroll
      for (int ni = 0; ni < 4; ni++)
        #pragma unroll
        for (int g = 0; g < 4; g++)
          Cx[(mi * 16 + ni * 4 + g) * 256 + ltid] = acc[mi][ni][g];
  }
  __syncthreads();
  if (!grp) {
    int w = ltid >> 6, lane = ltid & 63;
    int wm = w >> 1, wn = w & 1, q4 = lane >> 4, r = lane & 15;
    #pragma unroll
    for (int mi = 0; mi < 4; mi++)
      #pragma unroll
      for (int ni = 0; ni < 4; ni++) {
        int c = n0 + (ni & 1) * 64 + wn * 32 + (ni >> 1) * 16 + r;
        #pragma unroll
        for (int g = 0; g < 4; g++) {
          int t = m0 + wm * 64 + mi * 16 + q4 * 4 + g;
          out[(size_t)t * DM + c] = n2n(acc[mi][ni][g] + Cx[(mi * 16 + ni * 4 + g) * 256 + ltid]);
        }
      }
  }
}

// ---------------- launch ----------------
extern "C" void kernel_launch(void* const* d_in, const int* in_sizes, int n_in,
                              void* d_out, int out_size, void* d_ws, size_t ws_size,
                              hipStream_t stream) {
  const float* hs = (const float*)d_in[0];
  const float* Wq = (const float*)d_in[1];
  const float* Wk = (const float*)d_in[2];
  const float* Wv = (const float*)d_in[3];
  const float* Wo = (const float*)d_in[4];
  char* ws = (char*)d_ws;
  const size_t MB = 1024 * 1024;
  unsigned short* hsb = (unsigned short*)(ws + 0);         // 8 MB
  unsigned short* wqb = (unsigned short*)(ws + 8 * MB);    // 8 MB
  unsigned short* wkb = (unsigned short*)(ws + 16 * MB);   // 8 MB
  unsigned short* wvb = (unsigned short*)(ws + 24 * MB);   // 8 MB
  unsigned short* wob = (unsigned short*)(ws + 32 * MB);   // 8 MB
  unsigned short* qbf = (unsigned short*)(ws + 40 * MB);   // 8 MB
  unsigned short* kbf = (unsigned short*)(ws + 48 * MB);   // 8 MB
  unsigned short* vbT = (unsigned short*)(ws + 56 * MB);   // 8 MB
  unsigned short* atb = (unsigned short*)(ws + 64 * MB);   // 8 MB
  float* attnf_s = (float*)(ws + 72 * MB);                 // 2 MB (rows 1792..2047)
  float* cst = (float*)(ws + 106 * MB);                    // 512 KB
  float* snt = (float*)(ws + 106 * MB + 524288);           // 512 KB
  float* Ssum = (float*)(ws + 107 * MB);                   // 16 KB
  float* lst = (float*)(ws + 107 * MB + 16384);            // 128 B

  cvt_kernel<<<20992, 256, 0, stream>>>(hs, Wq, Wk, Wv, Wo, hsb, wqb, wkb, wvb, wob, cst, snt);
  gemm_qkv_kernel<<<dim3(16, 34), 256, 0, stream>>>(hsb, wqb, wkb, wvb, cst, snt, qbf, kbf, vbT);
  attn_kernel<<<dim3(32, 8), 256, 0, stream>>>(qbf, kbf, vbT, atb, attnf_s, Ssum, lst, 0);
  attn_kernel<<<dim3(32, 8), 256, 0, stream>>>(qbf, kbf, vbT, atb, attnf_s, Ssum, lst, 8);
  fixup_kernel<<<2048, 256, 0, stream>>>(attnf_s, Ssum, lst, vbT, atb);
  gemm_out_kernel<<<dim3(16, 16), 512, 0, stream>>>(atb, wob, (float*)d_out);
}

// Round 7
// 237.882 us; speedup vs baseline: 1.0980x; 1.0980x over previous
//
#include <hip/hip_runtime.h>
#include <stdint.h>

// ---------------- constants ----------------
#define T_SEQ 2048
#define DM    2048
#define NH    16
#define HD    128
#define SB    204          // int(0.1*2048)
#define EV    1229         // 2048 - 819
#define RB    819          // int(0.4*2048)
#define NRECF 818.0f       // 2048 - (EV+1)
#define LAST_START 1792    // (2047//256)*256
#define SCALE 0.08838834764831845f  // 1/sqrt(128)

typedef __attribute__((ext_vector_type(8))) short short8;
typedef __attribute__((ext_vector_type(4))) short short4v;
typedef __attribute__((ext_vector_type(4))) float f32x4;

__device__ __forceinline__ unsigned short f2bf(float f) {
  uint32_t u = __float_as_uint(f);
  u += 0x7fffu + ((u >> 16) & 1u);   // RNE
  return (unsigned short)(u >> 16);
}
__device__ __forceinline__ float bf2f(unsigned short s) {
  return __uint_as_float(((uint32_t)s) << 16);
}
__device__ __forceinline__ void gload16(const void* g, void* l) {
  __builtin_amdgcn_global_load_lds((const __attribute__((address_space(1))) void*)g,
                                   (__attribute__((address_space(3))) void*)l,
                                   16, 0, 0);
}
__device__ __forceinline__ float n2n(float v) {
  if (isnan(v)) return 0.0f;
  if (isinf(v)) return v > 0.0f ? 10000.0f : -10000.0f;
  return v;
}

// ---------------- 1. fp32 -> bf16 conversions + RoPE table (fused) ----------------
__global__ __launch_bounds__(256) void cvt_kernel(
    const float* __restrict__ hs, const float* __restrict__ wq,
    const float* __restrict__ wk, const float* __restrict__ wv,
    const float* __restrict__ wo, unsigned short* __restrict__ hsb,
    unsigned short* __restrict__ wqb, unsigned short* __restrict__ wkb,
    unsigned short* __restrict__ wvb, unsigned short* __restrict__ wob,
    float* __restrict__ cst, float* __restrict__ snt) {
  if (blockIdx.x >= 20480) {   // RoPE cos/sin table tail blocks
    int idx = (blockIdx.x - 20480) * 256 + threadIdx.x;   // 2048*64
    int t = idx >> 6, i = idx & 63;
    float inv = (float)exp(-(double)i * log(10000.0) / 64.0);
    float ang = (float)t * inv;
    cst[idx] = (float)cos((double)ang);
    snt[idx] = (float)sin((double)ang);
    return;
  }
  int gid = blockIdx.x * 256 + threadIdx.x;
  int region = gid >> 20;
  int off4 = (gid & 1048575) * 4;
  const float* src; unsigned short* dst;
  switch (region) {
    case 0: src = hs; dst = hsb; break;
    case 1: src = wq; dst = wqb; break;
    case 2: src = wk; dst = wkb; break;
    case 3: src = wv; dst = wvb; break;
    default: src = wo; dst = wob; break;
  }
  float4 v = *(const float4*)(src + off4);
  if (region == 0) { v.x = n2n(v.x); v.y = n2n(v.y); v.z = n2n(v.z); v.w = n2n(v.w); }
  ushort4 o;
  o.x = f2bf(v.x); o.y = f2bf(v.y); o.z = f2bf(v.z); o.w = f2bf(v.w);
  *(ushort4*)(dst + off4) = o;
}

// ---------------- shared BK=64 GEMM mainloop (single-buffer, proven round-0) ----------------
// C[128x128] tile, A[M,K] @ B[N,K]^T bf16. LDS rows = 128 B (8 x 16B chunks),
// XOR-swizzled: phys chunk = logical ^ (row & 7), folded into global src addr.
// tid is GROUP-LOCAL (0..255): callable by multi-group blocks whose groups share
// the workgroup barrier (identical barrier cadence in every group).
__device__ __forceinline__ void gemm_mainloop64(
    const unsigned short* __restrict__ A, const unsigned short* __restrict__ B,
    unsigned short* As, unsigned short* Bs, int m0, int n0, int k0, int ksteps,
    int tid, f32x4 (&acc)[4][4]) {
  int w = tid >> 6, lane = tid & 63;
  int wm = w >> 1, wn = w & 1;
  int q4 = lane >> 4, r = lane & 15;
  f32x4 zero = {0.f, 0.f, 0.f, 0.f};
  #pragma unroll
  for (int mi = 0; mi < 4; mi++)
    #pragma unroll
    for (int ni = 0; ni < 4; ni++) acc[mi][ni] = zero;
  int srow = w * 32 + (lane >> 3);
  int swz = ((lane & 7) ^ (lane >> 3)) * 16;
  const char* Ag = (const char*)(A + (size_t)(m0 + srow) * DM) + swz + k0 * 2;
  const char* Bg = (const char*)(B + (size_t)(n0 + srow) * DM) + swz + k0 * 2;
  unsigned short* Asl = As + w * 2048;
  unsigned short* Bsl = Bs + w * 2048;
  for (int s = 0; s < ksteps; s++) {
    __syncthreads();
    #pragma unroll
    for (int g = 0; g < 4; g++) {
      gload16(Ag + g * (8 * DM * 2), Asl + g * 512);
      gload16(Bg + g * (8 * DM * 2), Bsl + g * 512);
    }
    Ag += 128; Bg += 128;   // advance 64 cols
    __syncthreads();
    #pragma unroll
    for (int kh = 0; kh < 2; kh++) {
      int pcs = ((kh * 4 + q4) ^ (r & 7)) * 8;
      short8 a[4], b[4];
      #pragma unroll
      for (int mi = 0; mi < 4; mi++)
        a[mi] = *(const short8*)(As + (wm * 64 + mi * 16 + r) * 64 + pcs);
      #pragma unroll
      for (int ni = 0; ni < 4; ni++)
        b[ni] = *(const short8*)(Bs + ((ni & 1) * 64 + wn * 32 + (ni >> 1) * 16 + r) * 64 + pcs);
      #pragma unroll
      for (int mi = 0; mi < 4; mi++)
        #pragma unroll
        for (int ni = 0; ni < 4; ni++)
          acc[mi][ni] = __builtin_amdgcn_mfma_f32_16x16x32_bf16(a[mi], b[ni], acc[mi][ni], 0, 0, 0);
    }
  }
}

// ---------------- 3. fused QKV GEMM + RoPE / V-transpose, masked-row cut ----------------
// grid y in [0,34): y<16 -> Q tile y; y<25 -> K tile map[y-16]; else V tile map[y-25]
// where map = {0,1,9..15} (only M-tiles containing kept key rows [0,224)U[1216,2048)).
__global__ __launch_bounds__(256, 3) void gemm_qkv_kernel(
    const unsigned short* __restrict__ hsb, const unsigned short* __restrict__ wqb,
    const unsigned short* __restrict__ wkb, const unsigned short* __restrict__ wvb,
    const float* __restrict__ cst, const float* __restrict__ snt,
    unsigned short* __restrict__ qbf, unsigned short* __restrict__ kbf,
    unsigned short* __restrict__ vbT) {
  __shared__ __align__(16) unsigned short LDSBUF[17408];  // As(16KB)+Bs(16KB); vtile reuses
  unsigned short* As = LDSBUF;
  unsigned short* Bs = LDSBUF + 8192;
  int y = blockIdx.y;
  int z, mi;
  if (y < 16)      { z = 0; mi = y; }
  else if (y < 25) { z = 1; mi = y - 16; }
  else             { z = 2; mi = y - 25; }
  if (z) mi = (mi < 2) ? mi : mi + 7;
  const unsigned short* B = (z == 0) ? wqb : (z == 1) ? wkb : wvb;
  int m0 = mi * 128, n0 = blockIdx.x * 128;
  f32x4 acc[4][4];
  gemm_mainloop64(hsb, B, As, Bs, m0, n0, 0, DM / 64, threadIdx.x, acc);
  int tid = threadIdx.x, w = tid >> 6, lane = tid & 63;
  int wm = w >> 1, wn = w & 1, q4 = lane >> 4, r = lane & 15;
  int h = n0 >> 7;
  if (z < 2) {
    unsigned short* dst = (z == 0) ? qbf : kbf;
    #pragma unroll
    for (int mj = 0; mj < 4; mj++)
      #pragma unroll
      for (int p = 0; p < 2; p++) {
        int d = wn * 32 + p * 16 + r;
        #pragma unroll
        for (int g = 0; g < 4; g++) {
          int t = m0 + wm * 64 + mj * 16 + q4 * 4 + g;
          float c = cst[t * 64 + d], s = snt[t * 64 + d];
          float x0 = acc[mj][2 * p][g], x1 = acc[mj][2 * p + 1][g];
          dst[((size_t)h * T_SEQ + t) * HD + d]      = f2bf(x0 * c - x1 * s);
          dst[((size_t)h * T_SEQ + t) * HD + d + 64] = f2bf(x1 * c + x0 * s);
        }
      }
  } else {
    // transpose C tile (t,d) -> vbT[h][d][t] via LDS (Tpad=136)
    __syncthreads();
    #pragma unroll
    for (int mj = 0; mj < 4; mj++)
      #pragma unroll
      for (int ni = 0; ni < 4; ni++) {
        int c = (ni & 1) * 64 + wn * 32 + (ni >> 1) * 16 + r;
        int tl = wm * 64 + mj * 16 + q4 * 4;
        short4v pv;
        pv[0] = (short)f2bf(acc[mj][ni][0]);
        pv[1] = (short)f2bf(acc[mj][ni][1]);
        pv[2] = (short)f2bf(acc[mj][ni][2]);
        pv[3] = (short)f2bf(acc[mj][ni][3]);
        *(short4v*)(LDSBUF + c * 136 + tl) = pv;
      }
    __syncthreads();
    int d = tid >> 1, th = tid & 1;
    unsigned short* gdst = vbT + ((size_t)h * HD + d) * T_SEQ + m0 + th * 64;
    const unsigned short* lsrc = LDSBUF + d * 136 + th * 64;
    #pragma unroll
    for (int j = 0; j < 8; j++)
      *(short8*)(gdst + j * 8) = *(const short8*)(lsrc + j * 8);
  }
}

// ---------------- 4. flash attention, 64-key super-chunks, cross-iter dbuf ----------------
// Merged body (round-5): both 32-key sub-chunks in one pass with separate Ps
// buffers; setprio around MFMA clusters. Round-7: single launch restored +
// XCD head-clustering swizzle: 1-D grid, xcd = bid&7 (HW round-robin), each
// XCD owns exactly 2 heads -> per-XCD K/V working set 2MB (fits 4MB private
// L2; was 16MB = thrash). The 32 q-blocks re-reading each head's K/V slab
// become L2 hits.
__device__ __forceinline__ void attn_body2(
    int kb, const unsigned short* Kt0, const unsigned short* Kt1,
    const unsigned short* Vt0, const unsigned short* Vt1,
    const unsigned short* ind0, const unsigned short* ind1,
    unsigned short* Ps0, unsigned short* Ps1,
    const short8 (&aq)[4], f32x4 (&o)[8], f32x4& o9, float (&evf)[4],
    int q4, int r) {
  f32x4 zero = {0.f, 0.f, 0.f, 0.f};
  int rsw = (r >> 1) & 3;
  f32x4 sA0 = zero, sA1 = zero, sB0 = zero, sB1 = zero;
  __builtin_amdgcn_s_setprio(1);
  #pragma unroll
  for (int c = 0; c < 4; c++) {
    int pc = ((c * 4 + q4) ^ r) * 8;
    short8 kA0 = *(const short8*)(Kt0 + r * 128 + pc);
    short8 kA1 = *(const short8*)(Kt0 + (16 + r) * 128 + pc);
    short8 kB0 = *(const short8*)(Kt1 + r * 128 + pc);
    short8 kB1 = *(const short8*)(Kt1 + (16 + r) * 128 + pc);
    sA0 = __builtin_amdgcn_mfma_f32_16x16x32_bf16(aq[c], kA0, sA0, 0, 0, 0);
    sA1 = __builtin_amdgcn_mfma_f32_16x16x32_bf16(aq[c], kA1, sA1, 0, 0, 0);
    sB0 = __builtin_amdgcn_mfma_f32_16x16x32_bf16(aq[c], kB0, sB0, 0, 0, 0);
    sB1 = __builtin_amdgcn_mfma_f32_16x16x32_bf16(aq[c], kB1, sB1, 0, 0, 0);
  }
  __builtin_amdgcn_s_setprio(0);
  int kgA0 = kb + r, kgA1 = kb + 16 + r, kgB0 = kb + 32 + r, kgB1 = kb + 48 + r;
  bool keepA0 = (kgA0 < SB) || (kgA0 >= EV);
  bool keepA1 = (kgA1 < SB) || (kgA1 >= EV);
  bool keepB0 = (kgB0 < SB) || (kgB0 >= EV);
  bool keepB1 = (kgB1 < SB) || (kgB1 >= EV);
  #pragma unroll
  for (int g = 0; g < 4; g++) {
    float pA0 = keepA0 ? __expf(fmaf(sA0[g], SCALE, -8.0f)) : 0.0f;
    float pA1 = keepA1 ? __expf(fmaf(sA1[g], SCALE, -8.0f)) : 0.0f;
    float pB0 = keepB0 ? __expf(fmaf(sB0[g], SCALE, -8.0f)) : 0.0f;
    float pB1 = keepB1 ? __expf(fmaf(sB1[g], SCALE, -8.0f)) : 0.0f;
    if (kb == 1216 && kgA0 == EV) evf[g] = pA0;   // fp32 capture of p(k=1229)
    int row = q4 * 4 + g;
    int psw = (row >> 1) & 3;
    int c0 = (((r >> 3) ^ psw) * 8) + (r & 7);
    int c1 = ((((r >> 3) + 2) ^ psw) * 8) + (r & 7);
    Ps0[row * 32 + c0] = f2bf(pA0);
    Ps0[row * 32 + c1] = f2bf(pA1);
    Ps1[row * 32 + c0] = f2bf(pB0);
    Ps1[row * 32 + c1] = f2bf(pB1);
  }
  short8 pa0 = *(const short8*)(Ps0 + r * 32 + (q4 ^ rsw) * 8);
  short8 pa1 = *(const short8*)(Ps1 + r * 32 + (q4 ^ rsw) * 8);
  __builtin_amdgcn_s_setprio(1);
  #pragma unroll
  for (int ni = 0; ni < 8; ni++) {
    short8 bv0 = *(const short8*)(Vt0 + (ni * 16 + r) * 32 + (q4 ^ rsw) * 8);
    short8 bv1 = *(const short8*)(Vt1 + (ni * 16 + r) * 32 + (q4 ^ rsw) * 8);
    o[ni] = __builtin_amdgcn_mfma_f32_16x16x32_bf16(pa0, bv0, o[ni], 0, 0, 0);
    o[ni] = __builtin_amdgcn_mfma_f32_16x16x32_bf16(pa1, bv1, o[ni], 0, 0, 0);
  }
  short8 bi0 = *(const short8*)(ind0 + r * 32 + (q4 ^ rsw) * 8);
  short8 bi1 = *(const short8*)(ind1 + r * 32 + (q4 ^ rsw) * 8);
  o9 = __builtin_amdgcn_mfma_f32_16x16x32_bf16(pa0, bi0, o9, 0, 0, 0);
  o9 = __builtin_amdgcn_mfma_f32_16x16x32_bf16(pa1, bi1, o9, 0, 0, 0);
  __builtin_amdgcn_s_setprio(0);
}

__global__ __launch_bounds__(256, 2) void attn_kernel(
    const unsigned short* __restrict__ qbf, const unsigned short* __restrict__ kbf,
    const unsigned short* __restrict__ vbT, unsigned short* __restrict__ atb,
    float* __restrict__ attnf_s, float* __restrict__ Ssum, float* __restrict__ lst) {
  __shared__ __align__(16) unsigned short KtS[2][2][4096];  // [dbuf][sub][32x128u]
  __shared__ __align__(16) unsigned short VtS[2][2][4096];  // [dbuf][sub][128x32u]
  __shared__ __align__(16) unsigned short Ps[4][2][512];    // per-wave, per-sub-chunk
  __shared__ __align__(16) unsigned short Ind[3 * 512];
  int tid = threadIdx.x, w = tid >> 6, lane = tid & 63;
  int q4 = lane >> 4, r = lane & 15;
  // XCD head-clustering: 512 blocks, xcd = bid&7 (HW round-robin across 8 XCDs).
  // Each XCD gets 64 blocks = 2 heads x 32 q-tiles -> 2MB K/V set in 4MB L2.
  int bid = blockIdx.x;
  int xcd = bid & 7, j = bid >> 3;       // j in [0,64)
  int h = xcd * 2 + (j >> 5);            // 2 heads per XCD
  int qx = j & 31;                       // q-tile within head
  int qb = qx * 64 + w * 16;

  for (int idx = tid; idx < 3 * 512; idx += 256) {
    int v = idx >> 9, n = (idx >> 5) & 15, jj = idx & 31;
    float val = 0.f;
    if (n == 0) val = 1.f;
    else if (n == 1) val = (v == 1) ? (jj >= 14 ? 1.f : 0.f) : (v == 2 ? 1.f : 0.f);
    Ind[v * 512 + n * 32 + (((jj >> 3) ^ ((n >> 1) & 3)) * 8) + (jj & 7)] = f2bf(val);
  }

  short8 aq[4];
  {
    const unsigned short* qrow = qbf + ((size_t)h * T_SEQ + qb + r) * HD;
    #pragma unroll
    for (int c = 0; c < 4; c++) aq[c] = *(const short8*)(qrow + c * 32 + q4 * 8);
  }
  f32x4 zero = {0.f, 0.f, 0.f, 0.f};
  f32x4 o[8], o9;
  #pragma unroll
  for (int ni = 0; ni < 8; ni++) o[ni] = zero;
  o9 = zero;
  float evf[4] = {0.f, 0.f, 0.f, 0.f};

  const char* Kbase = (const char*)(kbf + (size_t)h * T_SEQ * HD);
  int krow0 = w * 8 + q4, krow1 = krow0 + 4;
  const char* Kg0 = Kbase + krow0 * 256 + ((r ^ (krow0 & 15)) * 16);
  const char* Kg1 = Kbase + krow1 * 256 + ((r ^ (krow1 & 15)) * 16);
  const char* Vbase = (const char*)(vbT + (size_t)h * HD * T_SEQ);
  int vsrc = ((lane & 3) ^ ((lane >> 3) & 3)) * 16;
  const char* Vg0 = Vbase + (size_t)(w * 32 + (lane >> 2)) * 4096 + vsrc;
  const char* Vg1 = Vg0 + 16 * 4096;

  auto issue_chunk = [&](int ci, int db) {
    int kb = (ci < 4) ? ci * 64 : 1216 + (ci - 4) * 64;
    gload16(Kg0 + kb * 256,         &KtS[db][0][w * 1024]);
    gload16(Kg1 + kb * 256,         &KtS[db][0][w * 1024 + 512]);
    gload16(Kg0 + (kb + 32) * 256,  &KtS[db][1][w * 1024]);
    gload16(Kg1 + (kb + 32) * 256,  &KtS[db][1][w * 1024 + 512]);
    gload16(Vg0 + kb * 2,           &VtS[db][0][w * 1024]);
    gload16(Vg1 + kb * 2,           &VtS[db][0][w * 1024 + 512]);
    gload16(Vg0 + (kb + 32) * 2,    &VtS[db][1][w * 1024]);
    gload16(Vg1 + (kb + 32) * 2,    &VtS[db][1][w * 1024 + 512]);
  };

  issue_chunk(0, 0);
  for (int ci = 0; ci < 17; ci++) {
    int db = ci & 1;
    int kb = (ci < 4) ? ci * 64 : 1216 + (ci - 4) * 64;
    const unsigned short* indA = Ind + ((ci < 4) ? 0 : (ci == 4) ? 512 : 1024);
    const unsigned short* indB = Ind + ((ci < 4) ? 0 : 1024);
    __syncthreads();
    if (ci < 16) issue_chunk(ci + 1, db ^ 1);
    attn_body2(kb, KtS[db][0], KtS[db][1], VtS[db][0], VtS[db][1],
               indA, indB, &Ps[w][0][0], &Ps[w][1][0], aq, o, o9, evf, q4, r);
  }

  float invl[4], srn[4], evn[4];
  #pragma unroll
  for (int g = 0; g < 4; g++) {
    float l  = __shfl(o9[g], lane & 48, 64);
    float sr = __shfl(o9[g], (lane & 48) | 1, 64);
    float ev = __shfl(evf[g], (lane & 48) | 13, 64);
    invl[g] = 1.0f / l;
    srn[g] = sr * invl[g];
    evn[g] = ev * invl[g];
  }
  if (qx < (LAST_START / 64)) {
    #pragma unroll
    for (int ni = 0; ni < 8; ni++)
      #pragma unroll
      for (int g = 0; g < 4; g++)
        atb[(size_t)(qb + q4 * 4 + g) * DM + h * HD + ni * 16 + r] = f2bf(o[ni][g] * invl[g]);
  } else {
    #pragma unroll
    for (int ni = 0; ni < 8; ni++)
      #pragma unroll
      for (int g = 0; g < 4; g++)
        attnf_s[(size_t)(qb - LAST_START + q4 * 4 + g) * DM + h * HD + ni * 16 + r] = o[ni][g] * invl[g];
  }
  if (r == 0) {
    #pragma unroll
    for (int g = 0; g < 4; g++) {
      int t = qb + q4 * 4 + g;
      if (t >= LAST_START) Ssum[h * 256 + (t - LAST_START)] = srn[g];
      if (t == T_SEQ - 1) { lst[h * 2] = evn[g]; lst[h * 2 + 1] = srn[g]; }
    }
  }
}

// ---------------- 5. rank-1 eviction fixup (rows >= 1792), bern inlined ----------------
__device__ __forceinline__ void tf_round(uint32_t& x0, uint32_t& x1, int rot) {
  x0 += x1;
  x1 = (x1 << rot) | (x1 >> (32 - rot));
  x1 ^= x0;
}
__device__ __forceinline__ float bern_scale(int hh, const float* lst) {
  const uint32_t k0 = 0u, k1 = 42u, k2 = 0x1BD11BDAu ^ k0 ^ k1;
  uint32_t x0 = (uint32_t)(hh & 7), x1 = (uint32_t)((hh & 7) + 8);
  x0 += k0; x1 += k1;
  tf_round(x0, x1, 13); tf_round(x0, x1, 15); tf_round(x0, x1, 26); tf_round(x0, x1, 6);
  x0 += k1; x1 += k2 + 1u;
  tf_round(x0, x1, 17); tf_round(x0, x1, 29); tf_round(x0, x1, 16); tf_round(x0, x1, 24);
  x0 += k2; x1 += k0 + 2u;
  tf_round(x0, x1, 13); tf_round(x0, x1, 15); tf_round(x0, x1, 26); tf_round(x0, x1, 6);
  x0 += k0; x1 += k1 + 3u;
  tf_round(x0, x1, 17); tf_round(x0, x1, 29); tf_round(x0, x1, 16); tf_round(x0, x1, 24);
  x0 += k1; x1 += k2 + 4u;
  tf_round(x0, x1, 13); tf_round(x0, x1, 15); tf_round(x0, x1, 26); tf_round(x0, x1, 6);
  x0 += k2; x1 += k0 + 5u;
  uint32_t bits = (hh < 8) ? x0 : x1;
  float u = __uint_as_float((bits >> 9) | 0x3f800000u) - 1.0f;
  float evp = lst[hh * 2], srp = lst[hh * 2 + 1];
  float mean = srp * (1.0f / NRECF) + 1e-6f;
  float p = evp / mean;
  p = fminf(fmaxf(p, 0.0f), 1.0f);
  if (!(p == p)) p = 0.0f;
  return (u < p) ? (1.0f / (float)RB) : 0.0f;
}

__global__ __launch_bounds__(256) void fixup_kernel(
    const float* __restrict__ attnf_s, const float* __restrict__ Ssum,
    const float* __restrict__ lst, const unsigned short* __restrict__ vbT,
    unsigned short* __restrict__ atb) {
  int idx = blockIdx.x * 256 + threadIdx.x;   // 256*2048
  int t2 = idx >> 11, n = idx & 2047;
  int h = n >> 7, d = n & 127;
  float bsc = bern_scale(h, lst);
  float v = attnf_s[idx];
  v += Ssum[h * 256 + t2] * bsc * bf2f(vbT[((size_t)h * HD + d) * T_SEQ + EV]);
  atb[(size_t)(t2 + LAST_START) * DM + n] = f2bf(v);
}

// ---------------- 6. output projection GEMM, in-block split-K=2, fused add+n2n ----------------
// 512 threads = 2 groups x 4 waves; group g computes K [g*1024, g*1024+1024) with
// the proven mainloop (identical barrier cadence in both groups -> shared
// __syncthreads aligns). Group 1 parks acc in LDS (lane-contiguous idx*256+ltid,
// conflict-free), group 0 adds + nan_to_num + writes fp32 d_out directly.
// Eliminates part0/part1 (32 MB writes + 32 MB reads) and add_kernel.
__global__ __launch_bounds__(512, 2) void gemm_out_kernel(
    const unsigned short* __restrict__ atb, const unsigned short* __restrict__ wob,
    float* __restrict__ out) {
  __shared__ __align__(16) unsigned short LDSBUF[32768];  // 64 KB: 2x(As+Bs); reused as f32 C-exchange
  int tid = threadIdx.x;
  int grp = tid >> 8;          // 0: K 0..1023, 1: K 1024..2047
  int ltid = tid & 255;
  unsigned short* As = LDSBUF + grp * 16384;
  unsigned short* Bs = As + 8192;
  int m0 = blockIdx.y * 128, n0 = blockIdx.x * 128;
  f32x4 acc[4][4];
  gemm_mainloop64(atb, wob, As, Bs, m0, n0, grp * 1024, 16, ltid, acc);
  float* Cx = (float*)LDSBUF;  // 64 KB = [64 idx][256 ltid] f32
  __syncthreads();             // all waves done with staging LDS
  if (grp) {
    #pragma unroll
    for (int mi = 0; mi < 4; mi++)
      #pragma unroll
      for (int ni = 0; ni < 4; ni++)
        #pragma unroll
        for (int g = 0; g < 4; g++)
          Cx[(mi * 16 + ni * 4 + g) * 256 + ltid] = acc[mi][ni][g];
  }
  __syncthreads();
  if (!grp) {
    int w = ltid >> 6, lane = ltid & 63;
    int wm = w >> 1, wn = w & 1, q4 = lane >> 4, r = lane & 15;
    #pragma unroll
    for (int mi = 0; mi < 4; mi++)
      #pragma unroll
      for (int ni = 0; ni < 4; ni++) {
        int c = n0 + (ni & 1) * 64 + wn * 32 + (ni >> 1) * 16 + r;
        #pragma unroll
        for (int g = 0; g < 4; g++) {
          int t = m0 + wm * 64 + mi * 16 + q4 * 4 + g;
          out[(size_t)t * DM + c] = n2n(acc[mi][ni][g] + Cx[(mi * 16 + ni * 4 + g) * 256 + ltid]);
        }
      }
  }
}

// ---------------- launch ----------------
extern "C" void kernel_launch(void* const* d_in, const int* in_sizes, int n_in,
                              void* d_out, int out_size, void* d_ws, size_t ws_size,
                              hipStream_t stream) {
  const float* hs = (const float*)d_in[0];
  const float* Wq = (const float*)d_in[1];
  const float* Wk = (const float*)d_in[2];
  const float* Wv = (const float*)d_in[3];
  const float* Wo = (const float*)d_in[4];
  char* ws = (char*)d_ws;
  const size_t MB = 1024 * 1024;
  unsigned short* hsb = (unsigned short*)(ws + 0);         // 8 MB
  unsigned short* wqb = (unsigned short*)(ws + 8 * MB);    // 8 MB
  unsigned short* wkb = (unsigned short*)(ws + 16 * MB);   // 8 MB
  unsigned short* wvb = (unsigned short*)(ws + 24 * MB);   // 8 MB
  unsigned short* wob = (unsigned short*)(ws + 32 * MB);   // 8 MB
  unsigned short* qbf = (unsigned short*)(ws + 40 * MB);   // 8 MB
  unsigned short* kbf = (unsigned short*)(ws + 48 * MB);   // 8 MB
  unsigned short* vbT = (unsigned short*)(ws + 56 * MB);   // 8 MB
  unsigned short* atb = (unsigned short*)(ws + 64 * MB);   // 8 MB
  float* attnf_s = (float*)(ws + 72 * MB);                 // 2 MB (rows 1792..2047)
  float* cst = (float*)(ws + 106 * MB);                    // 512 KB
  float* snt = (float*)(ws + 106 * MB + 524288);           // 512 KB
  float* Ssum = (float*)(ws + 107 * MB);                   // 16 KB
  float* lst = (float*)(ws + 107 * MB + 16384);            // 128 B

  cvt_kernel<<<20992, 256, 0, stream>>>(hs, Wq, Wk, Wv, Wo, hsb, wqb, wkb, wvb, wob, cst, snt);
  gemm_qkv_kernel<<<dim3(16, 34), 256, 0, stream>>>(hsb, wqb, wkb, wvb, cst, snt, qbf, kbf, vbT);
  attn_kernel<<<512, 256, 0, stream>>>(qbf, kbf, vbT, atb, attnf_s, Ssum, lst);
  fixup_kernel<<<2048, 256, 0, stream>>>(attnf_s, Ssum, lst, vbT, atb);
  gemm_out_kernel<<<dim3(16, 16), 512, 0, stream>>>(atb, wob, (float*)d_out);
}

// Round 8
// 233.444 us; speedup vs baseline: 1.1189x; 1.0190x over previous
//
#include <hip/hip_runtime.h>
#include <stdint.h>

// ---------------- constants ----------------
#define T_SEQ 2048
#define DM    2048
#define NH    16
#define HD    128
#define SB    204          // int(0.1*2048)
#define EV    1229         // 2048 - 819
#define RB    819          // int(0.4*2048)
#define NRECF 818.0f       // 2048 - (EV+1)
#define LAST_START 1792    // (2047//256)*256
#define SCALE 0.08838834764831845f  // 1/sqrt(128)

typedef __attribute__((ext_vector_type(8))) short short8;
typedef __attribute__((ext_vector_type(4))) short short4v;
typedef __attribute__((ext_vector_type(4))) float f32x4;

__device__ __forceinline__ unsigned short f2bf(float f) {
  uint32_t u = __float_as_uint(f);
  u += 0x7fffu + ((u >> 16) & 1u);   // RNE
  return (unsigned short)(u >> 16);
}
__device__ __forceinline__ float bf2f(unsigned short s) {
  return __uint_as_float(((uint32_t)s) << 16);
}
__device__ __forceinline__ void gload16(const void* g, void* l) {
  __builtin_amdgcn_global_load_lds((const __attribute__((address_space(1))) void*)g,
                                   (__attribute__((address_space(3))) void*)l,
                                   16, 0, 0);
}
__device__ __forceinline__ float n2n(float v) {
  if (isnan(v)) return 0.0f;
  if (isinf(v)) return v > 0.0f ? 10000.0f : -10000.0f;
  return v;
}

// ---------------- 1. fp32 -> bf16 conversions + RoPE table (fused) ----------------
__global__ __launch_bounds__(256) void cvt_kernel(
    const float* __restrict__ hs, const float* __restrict__ wq,
    const float* __restrict__ wk, const float* __restrict__ wv,
    const float* __restrict__ wo, unsigned short* __restrict__ hsb,
    unsigned short* __restrict__ wqb, unsigned short* __restrict__ wkb,
    unsigned short* __restrict__ wvb, unsigned short* __restrict__ wob,
    float* __restrict__ cst, float* __restrict__ snt) {
  if (blockIdx.x >= 20480) {   // RoPE cos/sin table tail blocks (f32 trig: tail
    // blocks dispatch last; f64 software transcendentals extended the kernel)
    int idx = (blockIdx.x - 20480) * 256 + threadIdx.x;   // 2048*64
    int t = idx >> 6, i = idx & 63;
    float inv = exp2f(-(float)i * 0.20761871929904988f);  // log2(10000)/64
    float ang = (float)t * inv;
    float s, c;
    sincosf(ang, &s, &c);
    cst[idx] = c;
    snt[idx] = s;
    return;
  }
  int gid = blockIdx.x * 256 + threadIdx.x;
  int region = gid >> 20;
  int off4 = (gid & 1048575) * 4;
  const float* src; unsigned short* dst;
  switch (region) {
    case 0: src = hs; dst = hsb; break;
    case 1: src = wq; dst = wqb; break;
    case 2: src = wk; dst = wkb; break;
    case 3: src = wv; dst = wvb; break;
    default: src = wo; dst = wob; break;
  }
  float4 v = *(const float4*)(src + off4);
  if (region == 0) { v.x = n2n(v.x); v.y = n2n(v.y); v.z = n2n(v.z); v.w = n2n(v.w); }
  ushort4 o;
  o.x = f2bf(v.x); o.y = f2bf(v.y); o.z = f2bf(v.z); o.w = f2bf(v.w);
  *(ushort4*)(dst + off4) = o;
}

// ---------------- shared BK=64 GEMM mainloop (single-buffer, proven round-0) ----------------
// C[128x128] tile, A[M,K] @ B[N,K]^T bf16. LDS rows = 128 B (8 x 16B chunks),
// XOR-swizzled: phys chunk = logical ^ (row & 7), folded into global src addr.
// tid is GROUP-LOCAL (0..255): callable by multi-group blocks whose groups share
// the workgroup barrier (identical barrier cadence in every group).
__device__ __forceinline__ void gemm_mainloop64(
    const unsigned short* __restrict__ A, const unsigned short* __restrict__ B,
    unsigned short* As, unsigned short* Bs, int m0, int n0, int k0, int ksteps,
    int tid, f32x4 (&acc)[4][4]) {
  int w = tid >> 6, lane = tid & 63;
  int wm = w >> 1, wn = w & 1;
  int q4 = lane >> 4, r = lane & 15;
  f32x4 zero = {0.f, 0.f, 0.f, 0.f};
  #pragma unroll
  for (int mi = 0; mi < 4; mi++)
    #pragma unroll
    for (int ni = 0; ni < 4; ni++) acc[mi][ni] = zero;
  int srow = w * 32 + (lane >> 3);
  int swz = ((lane & 7) ^ (lane >> 3)) * 16;
  const char* Ag = (const char*)(A + (size_t)(m0 + srow) * DM) + swz + k0 * 2;
  const char* Bg = (const char*)(B + (size_t)(n0 + srow) * DM) + swz + k0 * 2;
  unsigned short* Asl = As + w * 2048;
  unsigned short* Bsl = Bs + w * 2048;
  for (int s = 0; s < ksteps; s++) {
    __syncthreads();
    #pragma unroll
    for (int g = 0; g < 4; g++) {
      gload16(Ag + g * (8 * DM * 2), Asl + g * 512);
      gload16(Bg + g * (8 * DM * 2), Bsl + g * 512);
    }
    Ag += 128; Bg += 128;   // advance 64 cols
    __syncthreads();
    #pragma unroll
    for (int kh = 0; kh < 2; kh++) {
      int pcs = ((kh * 4 + q4) ^ (r & 7)) * 8;
      short8 a[4], b[4];
      #pragma unroll
      for (int mi = 0; mi < 4; mi++)
        a[mi] = *(const short8*)(As + (wm * 64 + mi * 16 + r) * 64 + pcs);
      #pragma unroll
      for (int ni = 0; ni < 4; ni++)
        b[ni] = *(const short8*)(Bs + ((ni & 1) * 64 + wn * 32 + (ni >> 1) * 16 + r) * 64 + pcs);
      #pragma unroll
      for (int mi = 0; mi < 4; mi++)
        #pragma unroll
        for (int ni = 0; ni < 4; ni++)
          acc[mi][ni] = __builtin_amdgcn_mfma_f32_16x16x32_bf16(a[mi], b[ni], acc[mi][ni], 0, 0, 0);
    }
  }
}

// ---------------- 3. fused QKV GEMM + RoPE / V-transpose, masked-row cut ----------------
// grid y in [0,34): y<16 -> Q tile y; y<25 -> K tile map[y-16]; else V tile map[y-25]
// where map = {0,1,9..15} (only M-tiles containing kept key rows [0,224)U[1216,2048)).
__global__ __launch_bounds__(256, 3) void gemm_qkv_kernel(
    const unsigned short* __restrict__ hsb, const unsigned short* __restrict__ wqb,
    const unsigned short* __restrict__ wkb, const unsigned short* __restrict__ wvb,
    const float* __restrict__ cst, const float* __restrict__ snt,
    unsigned short* __restrict__ qbf, unsigned short* __restrict__ kbf,
    unsigned short* __restrict__ vbT) {
  __shared__ __align__(16) unsigned short LDSBUF[17408];  // As(16KB)+Bs(16KB); vtile reuses
  unsigned short* As = LDSBUF;
  unsigned short* Bs = LDSBUF + 8192;
  int y = blockIdx.y;
  int z, mi;
  if (y < 16)      { z = 0; mi = y; }
  else if (y < 25) { z = 1; mi = y - 16; }
  else             { z = 2; mi = y - 25; }
  if (z) mi = (mi < 2) ? mi : mi + 7;
  const unsigned short* B = (z == 0) ? wqb : (z == 1) ? wkb : wvb;
  int m0 = mi * 128, n0 = blockIdx.x * 128;
  f32x4 acc[4][4];
  gemm_mainloop64(hsb, B, As, Bs, m0, n0, 0, DM / 64, threadIdx.x, acc);
  int tid = threadIdx.x, w = tid >> 6, lane = tid & 63;
  int wm = w >> 1, wn = w & 1, q4 = lane >> 4, r = lane & 15;
  int h = n0 >> 7;
  if (z < 2) {
    unsigned short* dst = (z == 0) ? qbf : kbf;
    #pragma unroll
    for (int mj = 0; mj < 4; mj++)
      #pragma unroll
      for (int p = 0; p < 2; p++) {
        int d = wn * 32 + p * 16 + r;
        #pragma unroll
        for (int g = 0; g < 4; g++) {
          int t = m0 + wm * 64 + mj * 16 + q4 * 4 + g;
          float c = cst[t * 64 + d], s = snt[t * 64 + d];
          float x0 = acc[mj][2 * p][g], x1 = acc[mj][2 * p + 1][g];
          dst[((size_t)h * T_SEQ + t) * HD + d]      = f2bf(x0 * c - x1 * s);
          dst[((size_t)h * T_SEQ + t) * HD + d + 64] = f2bf(x1 * c + x0 * s);
        }
      }
  } else {
    // transpose C tile (t,d) -> vbT[h][d][t] via LDS (Tpad=136)
    __syncthreads();
    #pragma unroll
    for (int mj = 0; mj < 4; mj++)
      #pragma unroll
      for (int ni = 0; ni < 4; ni++) {
        int c = (ni & 1) * 64 + wn * 32 + (ni >> 1) * 16 + r;
        int tl = wm * 64 + mj * 16 + q4 * 4;
        short4v pv;
        pv[0] = (short)f2bf(acc[mj][ni][0]);
        pv[1] = (short)f2bf(acc[mj][ni][1]);
        pv[2] = (short)f2bf(acc[mj][ni][2]);
        pv[3] = (short)f2bf(acc[mj][ni][3]);
        *(short4v*)(LDSBUF + c * 136 + tl) = pv;
      }
    __syncthreads();
    int d = tid >> 1, th = tid & 1;
    unsigned short* gdst = vbT + ((size_t)h * HD + d) * T_SEQ + m0 + th * 64;
    const unsigned short* lsrc = LDSBUF + d * 136 + th * 64;
    #pragma unroll
    for (int j = 0; j < 8; j++)
      *(short8*)(gdst + j * 8) = *(const short8*)(lsrc + j * 8);
  }
}

// ---------------- 4. flash attention, 64-key super-chunks, cross-iter dbuf ----------------
// Round-8: 512-thread blocks (8 waves) — 2x q-rows (128) per block share ONE
// staged K/V slab: staging traffic halves (278->139 MB), per-wave issue drops
// 8->4 gload16/chunk, per-barrier vmcnt drain shortens. Grid 256 (XCD
// head-clustered), 1 block/CU, 8 waves/CU (TLP unchanged).
__device__ __forceinline__ void attn_body2(
    int kb, const unsigned short* Kt0, const unsigned short* Kt1,
    const unsigned short* Vt0, const unsigned short* Vt1,
    const unsigned short* ind0, const unsigned short* ind1,
    unsigned short* Ps0, unsigned short* Ps1,
    const short8 (&aq)[4], f32x4 (&o)[8], f32x4& o9, float (&evf)[4],
    int q4, int r) {
  f32x4 zero = {0.f, 0.f, 0.f, 0.f};
  int rsw = (r >> 1) & 3;
  f32x4 sA0 = zero, sA1 = zero, sB0 = zero, sB1 = zero;
  __builtin_amdgcn_s_setprio(1);
  #pragma unroll
  for (int c = 0; c < 4; c++) {
    int pc = ((c * 4 + q4) ^ r) * 8;
    short8 kA0 = *(const short8*)(Kt0 + r * 128 + pc);
    short8 kA1 = *(const short8*)(Kt0 + (16 + r) * 128 + pc);
    short8 kB0 = *(const short8*)(Kt1 + r * 128 + pc);
    short8 kB1 = *(const short8*)(Kt1 + (16 + r) * 128 + pc);
    sA0 = __builtin_amdgcn_mfma_f32_16x16x32_bf16(aq[c], kA0, sA0, 0, 0, 0);
    sA1 = __builtin_amdgcn_mfma_f32_16x16x32_bf16(aq[c], kA1, sA1, 0, 0, 0);
    sB0 = __builtin_amdgcn_mfma_f32_16x16x32_bf16(aq[c], kB0, sB0, 0, 0, 0);
    sB1 = __builtin_amdgcn_mfma_f32_16x16x32_bf16(aq[c], kB1, sB1, 0, 0, 0);
  }
  __builtin_amdgcn_s_setprio(0);
  int kgA0 = kb + r, kgA1 = kb + 16 + r, kgB0 = kb + 32 + r, kgB1 = kb + 48 + r;
  bool keepA0 = (kgA0 < SB) || (kgA0 >= EV);
  bool keepA1 = (kgA1 < SB) || (kgA1 >= EV);
  bool keepB0 = (kgB0 < SB) || (kgB0 >= EV);
  bool keepB1 = (kgB1 < SB) || (kgB1 >= EV);
  #pragma unroll
  for (int g = 0; g < 4; g++) {
    float pA0 = keepA0 ? __expf(fmaf(sA0[g], SCALE, -8.0f)) : 0.0f;
    float pA1 = keepA1 ? __expf(fmaf(sA1[g], SCALE, -8.0f)) : 0.0f;
    float pB0 = keepB0 ? __expf(fmaf(sB0[g], SCALE, -8.0f)) : 0.0f;
    float pB1 = keepB1 ? __expf(fmaf(sB1[g], SCALE, -8.0f)) : 0.0f;
    if (kb == 1216 && kgA0 == EV) evf[g] = pA0;   // fp32 capture of p(k=1229)
    int row = q4 * 4 + g;
    int psw = (row >> 1) & 3;
    int c0 = (((r >> 3) ^ psw) * 8) + (r & 7);
    int c1 = ((((r >> 3) + 2) ^ psw) * 8) + (r & 7);
    Ps0[row * 32 + c0] = f2bf(pA0);
    Ps0[row * 32 + c1] = f2bf(pA1);
    Ps1[row * 32 + c0] = f2bf(pB0);
    Ps1[row * 32 + c1] = f2bf(pB1);
  }
  short8 pa0 = *(const short8*)(Ps0 + r * 32 + (q4 ^ rsw) * 8);
  short8 pa1 = *(const short8*)(Ps1 + r * 32 + (q4 ^ rsw) * 8);
  __builtin_amdgcn_s_setprio(1);
  #pragma unroll
  for (int ni = 0; ni < 8; ni++) {
    short8 bv0 = *(const short8*)(Vt0 + (ni * 16 + r) * 32 + (q4 ^ rsw) * 8);
    short8 bv1 = *(const short8*)(Vt1 + (ni * 16 + r) * 32 + (q4 ^ rsw) * 8);
    o[ni] = __builtin_amdgcn_mfma_f32_16x16x32_bf16(pa0, bv0, o[ni], 0, 0, 0);
    o[ni] = __builtin_amdgcn_mfma_f32_16x16x32_bf16(pa1, bv1, o[ni], 0, 0, 0);
  }
  short8 bi0 = *(const short8*)(ind0 + r * 32 + (q4 ^ rsw) * 8);
  short8 bi1 = *(const short8*)(ind1 + r * 32 + (q4 ^ rsw) * 8);
  o9 = __builtin_amdgcn_mfma_f32_16x16x32_bf16(pa0, bi0, o9, 0, 0, 0);
  o9 = __builtin_amdgcn_mfma_f32_16x16x32_bf16(pa1, bi1, o9, 0, 0, 0);
  __builtin_amdgcn_s_setprio(0);
}

__global__ __launch_bounds__(512, 1) void attn_kernel(
    const unsigned short* __restrict__ qbf, const unsigned short* __restrict__ kbf,
    const unsigned short* __restrict__ vbT, unsigned short* __restrict__ atb,
    float* __restrict__ attnf_s, float* __restrict__ Ssum, float* __restrict__ lst) {
  __shared__ __align__(16) unsigned short KtS[2][2][4096];  // [dbuf][sub][32x128u]
  __shared__ __align__(16) unsigned short VtS[2][2][4096];  // [dbuf][sub][128x32u]
  __shared__ __align__(16) unsigned short Ps[8][2][512];    // per-wave, per-sub-chunk
  __shared__ __align__(16) unsigned short Ind[3 * 512];
  int tid = threadIdx.x, w8 = tid >> 6, lane = tid & 63;
  int q4 = lane >> 4, r = lane & 15;
  // XCD head-clustering: 256 blocks, xcd = bid&7 -> 32 blocks/XCD = 2 heads x
  // 16 q-blocks of 128 rows.
  int bid = blockIdx.x;
  int xcd = bid & 7, j = bid >> 3;       // j in [0,32)
  int h = xcd * 2 + (j >> 4);            // 2 heads per XCD
  int qx = j & 15;                       // 128-row q-block within head
  int qb = qx * 128 + w8 * 16;

  for (int idx = tid; idx < 3 * 512; idx += 512) {
    int v = idx >> 9, n = (idx >> 5) & 15, jj = idx & 31;
    float val = 0.f;
    if (n == 0) val = 1.f;
    else if (n == 1) val = (v == 1) ? (jj >= 14 ? 1.f : 0.f) : (v == 2 ? 1.f : 0.f);
    Ind[v * 512 + n * 32 + (((jj >> 3) ^ ((n >> 1) & 3)) * 8) + (jj & 7)] = f2bf(val);
  }

  short8 aq[4];
  {
    const unsigned short* qrow = qbf + ((size_t)h * T_SEQ + qb + r) * HD;
    #pragma unroll
    for (int c = 0; c < 4; c++) aq[c] = *(const short8*)(qrow + c * 32 + q4 * 8);
  }
  f32x4 zero = {0.f, 0.f, 0.f, 0.f};
  f32x4 o[8], o9;
  #pragma unroll
  for (int ni = 0; ni < 8; ni++) o[ni] = zero;
  o9 = zero;
  float evf[4] = {0.f, 0.f, 0.f, 0.f};

  // Staging: 8 waves cover 32 K-rows (4/wave) and 128 V d-rows (16/wave) per sub.
  const char* Kbase = (const char*)(kbf + (size_t)h * T_SEQ * HD);
  int krow = w8 * 4 + q4;
  const char* Kg = Kbase + krow * 256 + ((r ^ (krow & 15)) * 16);
  const char* Vbase = (const char*)(vbT + (size_t)h * HD * T_SEQ);
  int vsrc = ((lane & 3) ^ ((lane >> 3) & 3)) * 16;
  const char* Vg = Vbase + (size_t)(w8 * 16 + (lane >> 2)) * 4096 + vsrc;

  auto issue_chunk = [&](int ci, int db) {
    int kb = (ci < 4) ? ci * 64 : 1216 + (ci - 4) * 64;
    gload16(Kg + kb * 256,        &KtS[db][0][w8 * 512]);
    gload16(Kg + (kb + 32) * 256, &KtS[db][1][w8 * 512]);
    gload16(Vg + kb * 2,          &VtS[db][0][w8 * 512]);
    gload16(Vg + (kb + 32) * 2,   &VtS[db][1][w8 * 512]);
  };

  issue_chunk(0, 0);
  for (int ci = 0; ci < 17; ci++) {
    int db = ci & 1;
    int kb = (ci < 4) ? ci * 64 : 1216 + (ci - 4) * 64;
    const unsigned short* indA = Ind + ((ci < 4) ? 0 : (ci == 4) ? 512 : 1024);
    const unsigned short* indB = Ind + ((ci < 4) ? 0 : 1024);
    __syncthreads();
    if (ci < 16) issue_chunk(ci + 1, db ^ 1);
    attn_body2(kb, KtS[db][0], KtS[db][1], VtS[db][0], VtS[db][1],
               indA, indB, &Ps[w8][0][0], &Ps[w8][1][0], aq, o, o9, evf, q4, r);
  }

  float invl[4], srn[4], evn[4];
  #pragma unroll
  for (int g = 0; g < 4; g++) {
    float l  = __shfl(o9[g], lane & 48, 64);
    float sr = __shfl(o9[g], (lane & 48) | 1, 64);
    float ev = __shfl(evf[g], (lane & 48) | 13, 64);
    invl[g] = 1.0f / l;
    srn[g] = sr * invl[g];
    evn[g] = ev * invl[g];
  }
  if (qx < 14) {   // rows < 1792 (qx*128+127 <= 1791 for qx<=13)
    #pragma unroll
    for (int ni = 0; ni < 8; ni++)
      #pragma unroll
      for (int g = 0; g < 4; g++)
        atb[(size_t)(qb + q4 * 4 + g) * DM + h * HD + ni * 16 + r] = f2bf(o[ni][g] * invl[g]);
  } else {
    #pragma unroll
    for (int ni = 0; ni < 8; ni++)
      #pragma unroll
      for (int g = 0; g < 4; g++)
        attnf_s[(size_t)(qb - LAST_START + q4 * 4 + g) * DM + h * HD + ni * 16 + r] = o[ni][g] * invl[g];
  }
  if (r == 0) {
    #pragma unroll
    for (int g = 0; g < 4; g++) {
      int t = qb + q4 * 4 + g;
      if (t >= LAST_START) Ssum[h * 256 + (t - LAST_START)] = srn[g];
      if (t == T_SEQ - 1) { lst[h * 2] = evn[g]; lst[h * 2 + 1] = srn[g]; }
    }
  }
}

// ---------------- 5. rank-1 eviction fixup (rows >= 1792), bern inlined, x4 vec ----------------
__device__ __forceinline__ void tf_round(uint32_t& x0, uint32_t& x1, int rot) {
  x0 += x1;
  x1 = (x1 << rot) | (x1 >> (32 - rot));
  x1 ^= x0;
}
__device__ __forceinline__ float bern_scale(int hh, const float* lst) {
  const uint32_t k0 = 0u, k1 = 42u, k2 = 0x1BD11BDAu ^ k0 ^ k1;
  uint32_t x0 = (uint32_t)(hh & 7), x1 = (uint32_t)((hh & 7) + 8);
  x0 += k0; x1 += k1;
  tf_round(x0, x1, 13); tf_round(x0, x1, 15); tf_round(x0, x1, 26); tf_round(x0, x1, 6);
  x0 += k1; x1 += k2 + 1u;
  tf_round(x0, x1, 17); tf_round(x0, x1, 29); tf_round(x0, x1, 16); tf_round(x0, x1, 24);
  x0 += k2; x1 += k0 + 2u;
  tf_round(x0, x1, 13); tf_round(x0, x1, 15); tf_round(x0, x1, 26); tf_round(x0, x1, 6);
  x0 += k0; x1 += k1 + 3u;
  tf_round(x0, x1, 17); tf_round(x0, x1, 29); tf_round(x0, x1, 16); tf_round(x0, x1, 24);
  x0 += k1; x1 += k2 + 4u;
  tf_round(x0, x1, 13); tf_round(x0, x1, 15); tf_round(x0, x1, 26); tf_round(x0, x1, 6);
  x0 += k2; x1 += k0 + 5u;
  uint32_t bits = (hh < 8) ? x0 : x1;
  float u = __uint_as_float((bits >> 9) | 0x3f800000u) - 1.0f;
  float evp = lst[hh * 2], srp = lst[hh * 2 + 1];
  float mean = srp * (1.0f / NRECF) + 1e-6f;
  float p = evp / mean;
  p = fminf(fmaxf(p, 0.0f), 1.0f);
  if (!(p == p)) p = 0.0f;
  return (u < p) ? (1.0f / (float)RB) : 0.0f;
}

__global__ __launch_bounds__(256) void fixup_kernel(
    const float* __restrict__ attnf_s, const float* __restrict__ Ssum,
    const float* __restrict__ lst, const unsigned short* __restrict__ vbT,
    unsigned short* __restrict__ atb) {
  int idx = (blockIdx.x * 256 + threadIdx.x) * 4;   // 4 elems/thread, same (t2,h)
  int t2 = idx >> 11, n = idx & 2047;
  int h = n >> 7, d = n & 127;
  float bsc = bern_scale(h, lst) * Ssum[h * 256 + t2];
  float4 v = *(const float4*)(attnf_s + idx);
  const unsigned short* vrow = vbT + ((size_t)h * HD + d) * T_SEQ + EV;
  ushort4 ov;
  ov.x = f2bf(v.x + bsc * bf2f(vrow[0]));
  ov.y = f2bf(v.y + bsc * bf2f(vrow[T_SEQ]));
  ov.z = f2bf(v.z + bsc * bf2f(vrow[2 * T_SEQ]));
  ov.w = f2bf(v.w + bsc * bf2f(vrow[3 * T_SEQ]));
  *(ushort4*)(atb + (size_t)(t2 + LAST_START) * DM + n) = ov;
}

// ---------------- 6. output projection GEMM, in-block split-K=2, fused add+n2n ----------------
// 512 threads = 2 groups x 4 waves; group g computes K [g*1024, g*1024+1024) with
// the proven mainloop (identical barrier cadence in both groups -> shared
// __syncthreads aligns). Group 1 parks acc in LDS (lane-contiguous idx*256+ltid,
// conflict-free), group 0 adds + nan_to_num + writes fp32 d_out directly.
__global__ __launch_bounds__(512, 2) void gemm_out_kernel(
    const unsigned short* __restrict__ atb, const unsigned short* __restrict__ wob,
    float* __restrict__ out) {
  __shared__ __align__(16) unsigned short LDSBUF[32768];  // 64 KB: 2x(As+Bs); reused as f32 C-exchange
  int tid = threadIdx.x;
  int grp = tid >> 8;          // 0: K 0..1023, 1: K 1024..2047
  int ltid = tid & 255;
  unsigned short* As = LDSBUF + grp * 16384;
  unsigned short* Bs = As + 8192;
  int m0 = blockIdx.y * 128, n0 = blockIdx.x * 128;
  f32x4 acc[4][4];
  gemm_mainloop64(atb, wob, As, Bs, m0, n0, grp * 1024, 16, ltid, acc);
  float* Cx = (float*)LDSBUF;  // 64 KB = [64 idx][256 ltid] f32
  __syncthreads();             // all waves done with staging LDS
  if (grp) {
    #pragma unroll
    for (int mi = 0; mi < 4; mi++)
      #pragma unroll
      for (int ni = 0; ni < 4; ni++)
        #pragma unroll
        for (int g = 0; g < 4; g++)
          Cx[(mi * 16 + ni * 4 + g) * 256 + ltid] = acc[mi][ni][g];
  }
  __syncthreads();
  if (!grp) {
    int w = ltid >> 6, lane = ltid & 63;
    int wm = w >> 1, wn = w & 1, q4 = lane >> 4, r = lane & 15;
    #pragma unroll
    for (int mi = 0; mi < 4; mi++)
      #pragma unroll
      for (int ni = 0; ni < 4; ni++) {
        int c = n0 + (ni & 1) * 64 + wn * 32 + (ni >> 1) * 16 + r;
        #pragma unroll
        for (int g = 0; g < 4; g++) {
          int t = m0 + wm * 64 + mi * 16 + q4 * 4 + g;
          out[(size_t)t * DM + c] = n2n(acc[mi][ni][g] + Cx[(mi * 16 + ni * 4 + g) * 256 + ltid]);
        }
      }
  }
}

// ---------------- launch ----------------
extern "C" void kernel_launch(void* const* d_in, const int* in_sizes, int n_in,
                              void* d_out, int out_size, void* d_ws, size_t ws_size,
                              hipStream_t stream) {
  const float* hs = (const float*)d_in[0];
  const float* Wq = (const float*)d_in[1];
  const float* Wk = (const float*)d_in[2];
  const float* Wv = (const float*)d_in[3];
  const float* Wo = (const float*)d_in[4];
  char* ws = (char*)d_ws;
  const size_t MB = 1024 * 1024;
  unsigned short* hsb = (unsigned short*)(ws + 0);         // 8 MB
  unsigned short* wqb = (unsigned short*)(ws + 8 * MB);    // 8 MB
  unsigned short* wkb = (unsigned short*)(ws + 16 * MB);   // 8 MB
  unsigned short* wvb = (unsigned short*)(ws + 24 * MB);   // 8 MB
  unsigned short* wob = (unsigned short*)(ws + 32 * MB);   // 8 MB
  unsigned short* qbf = (unsigned short*)(ws + 40 * MB);   // 8 MB
  unsigned short* kbf = (unsigned short*)(ws + 48 * MB);   // 8 MB
  unsigned short* vbT = (unsigned short*)(ws + 56 * MB);   // 8 MB
  unsigned short* atb = (unsigned short*)(ws + 64 * MB);   // 8 MB
  float* attnf_s = (float*)(ws + 72 * MB);                 // 2 MB (rows 1792..2047)
  float* cst = (float*)(ws + 106 * MB);                    // 512 KB
  float* snt = (float*)(ws + 106 * MB + 524288);           // 512 KB
  float* Ssum = (float*)(ws + 107 * MB);                   // 16 KB
  float* lst = (float*)(ws + 107 * MB + 16384);            // 128 B

  cvt_kernel<<<20992, 256, 0, stream>>>(hs, Wq, Wk, Wv, Wo, hsb, wqb, wkb, wvb, wob, cst, snt);
  gemm_qkv_kernel<<<dim3(16, 34), 256, 0, stream>>>(hsb, wqb, wkb, wvb, cst, snt, qbf, kbf, vbT);
  attn_kernel<<<256, 512, 0, stream>>>(qbf, kbf, vbT, atb, attnf_s, Ssum, lst);
  fixup_kernel<<<512, 256, 0, stream>>>(attnf_s, Ssum, lst, vbT, atb);
  gemm_out_kernel<<<dim3(16, 16), 512, 0, stream>>>(atb, wob, (float*)d_out);
}